// Round 17
// baseline (580.298 us; speedup 1.0000x reference)
//
#include <hip/hip_runtime.h>

#define Hd 256
#define NNODE 10000
#define NE1 131072
#define NE2 65536
#define TROWS 4097
#define TLD 1792     // 7 * 256 packed table columns

typedef __attribute__((ext_vector_type(8))) short bf16x8;
typedef __attribute__((ext_vector_type(4))) float f32x4;

#define MFMA16(a, b, c) __builtin_amdgcn_mfma_f32_16x16x32_bf16((a), (b), (c), 0, 0, 0)

__device__ __forceinline__ float b2f(ushort u) { return __uint_as_float(((unsigned)u) << 16); }
__device__ __forceinline__ ushort f2b(float f) {
  unsigned u = __float_as_uint(f);
  return (ushort)((u + 0x7fffu + ((u >> 16) & 1u)) >> 16);
}

// ---------------- small kernels ----------------

__global__ void time_mlp_k(const float* __restrict__ tval,
                           const float* __restrict__ W0, const float* __restrict__ b0,
                           const float* __restrict__ W1, const float* __restrict__ b1,
                           const float* __restrict__ W2, const float* __restrict__ b2,
                           float* __restrict__ tenc) {
  __shared__ float h0[Hd], h1[Hd];
  int b = blockIdx.x, j = threadIdx.x;
  float t = tval[b];
  h0[j] = fmaxf(t * W0[j] + b0[j], 0.f);
  __syncthreads();
  float a = b1[j];
  for (int k = 0; k < Hd; ++k) a += h0[k] * W1[k * Hd + j];
  h1[j] = fmaxf(a, 0.f);
  __syncthreads();
  float c = b2[j];
  for (int k = 0; k < Hd; ++k) c += h1[k] * W2[k * Hd + j];
  tenc[b * Hd + j] = c;
}

__global__ void build_x0_k(const int* __restrict__ batch, const float* __restrict__ tenc,
                           ushort* __restrict__ x0) {
  int idx = blockIdx.x * 256 + threadIdx.x;
  int n = idx >> 9;
  x0[idx] = f2b(tenc[batch[n] * Hd + (idx & 255)]);
}

__global__ void init_small_k(int* __restrict__ cnt1, int* __restrict__ cur1,
                             int* __restrict__ cnt2, int* __restrict__ cur2,
                             float* __restrict__ zerob, float* __restrict__ biascat,
                             const float* __restrict__ gg_bl, const float* __restrict__ gg_br,
                             const float* __restrict__ gf_bl, const float* __restrict__ gf_br) {
  int i = blockIdx.x * 256 + threadIdx.x;
  if (i < NNODE) { cnt1[i] = 0; cur1[i] = 0; cnt2[i] = 0; cur2[i] = 0; return; }
  i -= NNODE;
  if (i < 512) { zerob[i] = 0.f; return; }
  i -= 512;
  if (i < 6144) {
    int layer = i >> 10, c = i & 1023;
    float v;
    if (c < 256)      v = gg_bl[layer * 256 + c];
    else if (c < 512) v = gg_br[layer * 256 + c - 256];
    else if (c < 768) v = gf_bl[layer * 256 + c - 512];
    else              v = gf_br[layer * 256 + c - 768];
    biascat[layer * 1024 + c] = v;
  }
}

// Packed fold: WcatT[y][n][k] = sum_j W2[k][j] * Wy[j][n]  (y<6: We[2i+g]; y=6: dec_W0c)
__global__ void fold2_k(const float* __restrict__ gg_We, const float* __restrict__ gf_We,
                        const float* __restrict__ dec_W0, const float* __restrict__ dec_b0,
                        const float* __restrict__ eeW2, const float* __restrict__ eeb2,
                        ushort* __restrict__ WcatT, float* __restrict__ bcat) {
  __shared__ float col[256];
  int n = blockIdx.x, y = blockIdx.y, k = threadIdx.x;
  if (y < 6) {
    int i = y >> 1, g = y & 1;
    const float* src = (g == 0 ? gg_We : gf_We) + (size_t)i * 65536;
    col[k] = src[(size_t)k * 256 + n];
  } else {
    col[k] = dec_W0[(size_t)(1024 + k) * 256 + n];
  }
  __syncthreads();
  float acc = 0.f;
  const float* w2row = eeW2 + (size_t)k * 256;
  for (int j = 0; j < 256; ++j) acc += w2row[j] * col[j];
  WcatT[((size_t)y * 256 + n) * 256 + k] = f2b(acc);
  if (k == 0) {
    float bb = (y == 6) ? dec_b0[n] : 0.f;
    for (int j = 0; j < 256; ++j) bb += eeb2[j] * col[j];
    bcat[y * 256 + n] = bb;
  }
}

// h0b[i][j] = bf16(relu((i/4096)*W0[j] + b0[j]))   (rank-1, elementwise)
__global__ void build_h0_k(const float* __restrict__ W0, const float* __restrict__ b0,
                           ushort* __restrict__ h0b) {
  int i = blockIdx.x, j = threadIdx.x;
  float a = (float)i / 4096.f;
  h0b[(size_t)i * 256 + j] = f2b(fmaxf(a * W0[j] + b0[j], 0.f));
}

// ---------------- merged weight transposes ----------------
struct TT { const float* src; ushort* dst; int K; int n_off; int ld; int start; };
struct TransArgs { TT t[24]; };

__global__ void trans_all_k(TransArgs a) {
  int b = blockIdx.x;
  int ti = 0;
  while (ti + 1 < 24 && a.t[ti + 1].start <= b) ++ti;
  TT tk = a.t[ti];
  int lb = b - tk.start;
  int gx = tk.K >> 5;
  int k0 = (lb % gx) * 32, n0 = (lb / gx) * 32;
  __shared__ float t[32][33];
  int tx = threadIdx.x & 31, ty = threadIdx.x >> 5;
#pragma unroll
  for (int p = 0; p < 4; ++p)
    t[ty + 8 * p][tx] = tk.src[(size_t)(k0 + ty + 8 * p) * 256 + n0 + tx];
  __syncthreads();
#pragma unroll
  for (int p = 0; p < 4; ++p)
    tk.dst[(size_t)(tk.n_off + n0 + ty + 8 * p) * tk.ld + k0 + tx] = f2b(t[tx][ty + 8 * p]);
}

// ---------------- CSR build (by dst) ----------------

__global__ void deg_all_k(const int* __restrict__ dst1, int* __restrict__ cnt1,
                          const int* __restrict__ dst2, int* __restrict__ cnt2) {
  int e = blockIdx.x * 256 + threadIdx.x;
  if (e < NE1) atomicAdd(cnt1 + dst1[e], 1);
  else if (e - NE1 < NE2) atomicAdd(cnt2 + dst2[e - NE1], 1);
}

__global__ void scan_k(const int* __restrict__ cnt1, int* __restrict__ rs1,
                       const int* __restrict__ cnt2, int* __restrict__ rs2) {
  const int g = blockIdx.x;
  const int* cnt = g ? cnt2 : cnt1;
  int* rowstart = g ? rs2 : rs1;
  const int E = g ? NE2 : NE1;
  __shared__ int part[626];
  int t = threadIdx.x;
  if (t < 625) {
    int s = 0;
#pragma unroll
    for (int i = 0; i < 16; ++i) s += cnt[t * 16 + i];
    part[t] = s;
  }
  __syncthreads();
  if (t == 0) {
    int run = 0;
    for (int i = 0; i < 625; ++i) { int v = part[i]; part[i] = run; run += v; }
  }
  __syncthreads();
  if (t < 625) {
    int off = part[t];
#pragma unroll
    for (int i = 0; i < 16; ++i) { rowstart[t * 16 + i] = off; off += cnt[t * 16 + i]; }
  }
  if (t == 0) rowstart[NNODE] = E;
}

// fill CSR + CSR-ordered side arrays
__global__ void fill_all_k(const int* __restrict__ dst1, const int* __restrict__ rs1,
                           int* __restrict__ cur1, int* __restrict__ eid1,
                           const int* __restrict__ src1, const float* __restrict__ eattr1,
                           int* __restrict__ srcs1, float* __restrict__ attrs1,
                           int* __restrict__ dsts1,
                           const int* __restrict__ dst2, const int* __restrict__ rs2,
                           int* __restrict__ cur2,
                           const int* __restrict__ src2, const float* __restrict__ eattr2,
                           int* __restrict__ srcs2, float* __restrict__ attrs2) {
  int e = blockIdx.x * 256 + threadIdx.x;
  if (e < NE1) {
    int d = dst1[e];
    int idx = rs1[d] + atomicAdd(cur1 + d, 1);
    eid1[idx] = e;
    srcs1[idx] = src1[e];
    attrs1[idx] = eattr1[e];
    dsts1[idx] = d;
  } else if (e - NE1 < NE2) {
    int e2 = e - NE1;
    int d = dst2[e2];
    int idx = rs2[d] + atomicAdd(cur2 + d, 1);
    srcs2[idx] = src2[e2];
    attrs2[idx] = eattr2[e2];
  }
}

// ---------------- fused logit + online-softmax aggregate ----------------
// 4 waves per node (stride-4 interleave), pipelined gather, NN table lookup,
// 4-way online-softmax merge through LDS. grid = 2*NNODE blocks (1 node/block).
__global__ __launch_bounds__(256) void attagg_k(
    const ushort* __restrict__ T, int tcol1, int tcol2,
    const float* __restrict__ att1, const float* __restrict__ att2,
    const ushort* __restrict__ xlr,
    const int* __restrict__ srcs1, const float* __restrict__ attrs1,
    const int* __restrict__ srcs2, const float* __restrict__ attrs2,
    const int* __restrict__ rs1, const int* __restrict__ rs2,
    const float* __restrict__ bias1, const float* __restrict__ bias2,
    ushort* __restrict__ xnext) {
  __shared__ float att_s[256], bias_s[256];
  __shared__ float acbuf[3][256];
  __shared__ float mden[3][2];
  const int tid = threadIdx.x;
  const bool g1 = blockIdx.x < NNODE;
  const int nid = g1 ? blockIdx.x : blockIdx.x - NNODE;
  att_s[tid] = g1 ? att1[tid] : att2[tid];
  bias_s[tid] = g1 ? bias1[tid] : bias2[tid];
  __syncthreads();
  const int sub = tid >> 6, lane = tid & 63;
  const int* srcs = g1 ? srcs1 : srcs2;
  const float* attrs = g1 ? attrs1 : attrs2;
  const int* rowstart = g1 ? rs1 : rs2;
  const int goff = g1 ? 0 : 512;
  const int colbase = g1 ? 0 : 256;
  const ushort* Tg = T + (g1 ? tcol1 : tcol2);
  const int c = lane * 4;
  ushort4 xr4 = *(const ushort4*)(xlr + (size_t)nid * 1024 + goff + 256 + c);
  const float xr0 = b2f(xr4.x), xr1 = b2f(xr4.y), xr2 = b2f(xr4.z), xr3 = b2f(xr4.w);
  const float a0 = att_s[c], a1 = att_s[c + 1];
  const float a2 = att_s[c + 2], a3 = att_s[c + 3];
  const int s0 = rowstart[nid], s1 = rowstart[nid + 1];
  float m = -1e30f;
  float den = 0.f, ac0 = 0.f, ac1 = 0.f, ac2 = 0.f, ac3 = 0.f;
  {
    int i = s0 + sub;
    if (i < s1) {
      ushort4 xv, lo;
      {  // prologue (nearest-neighbor table row)
        int s = srcs[i];
        int i0 = (int)(attrs[i] * 4096.f + 0.5f);
        i0 = i0 < 0 ? 0 : (i0 > 4096 ? 4096 : i0);
        lo = *(const ushort4*)(Tg + (size_t)i0 * TLD + c);
        xv = *(const ushort4*)(xlr + (size_t)s * 1024 + goff + c);
      }
      for (; i < s1; i += 4) {
        ushort4 xv_c = xv, lo_c = lo;
        if (i + 4 < s1) {  // prefetch next edge (this wave's quarter)
          int s = srcs[i + 4];
          int i0 = (int)(attrs[i + 4] * 4096.f + 0.5f);
          i0 = i0 < 0 ? 0 : (i0 > 4096 ? 4096 : i0);
          lo = *(const ushort4*)(Tg + (size_t)i0 * TLD + c);
          xv = *(const ushort4*)(xlr + (size_t)s * 1024 + goff + c);
        }
        float x0 = b2f(xv_c.x), x1 = b2f(xv_c.y), x2 = b2f(xv_c.z), x3 = b2f(xv_c.w);
        float z0 = x0 + xr0 + b2f(lo_c.x);
        float z1 = x1 + xr1 + b2f(lo_c.y);
        float z2 = x2 + xr2 + b2f(lo_c.z);
        float z3 = x3 + xr3 + b2f(lo_c.w);
        z0 = z0 > 0.f ? z0 : 0.2f * z0;
        z1 = z1 > 0.f ? z1 : 0.2f * z1;
        z2 = z2 > 0.f ? z2 : 0.2f * z2;
        z3 = z3 > 0.f ? z3 : 0.2f * z3;
        float p = z0 * a0 + z1 * a1 + z2 * a2 + z3 * a3;
#pragma unroll
        for (int dd = 1; dd < 64; dd <<= 1) p += __shfl_xor(p, dd);
        float mn = fmaxf(m, p);
        float sc = __expf(m - mn);
        float ww = __expf(p - mn);
        den = den * sc + ww;
        ac0 = ac0 * sc + ww * x0;
        ac1 = ac1 * sc + ww * x1;
        ac2 = ac2 * sc + ww * x2;
        ac3 = ac3 * sc + ww * x3;
        m = mn;
      }
    }
  }
  // 4-way merge through LDS
  if (sub > 0) {
    acbuf[sub - 1][c + 0] = ac0;
    acbuf[sub - 1][c + 1] = ac1;
    acbuf[sub - 1][c + 2] = ac2;
    acbuf[sub - 1][c + 3] = ac3;
    if (lane == 0) { mden[sub - 1][0] = m; mden[sub - 1][1] = den; }
  }
  __syncthreads();
  if (sub == 0) {
#pragma unroll
    for (int t = 0; t < 3; ++t) {
      float m1 = mden[t][0], den1 = mden[t][1];
      float mn = fmaxf(m, m1);
      float sc0 = __expf(m - mn), sc1 = __expf(m1 - mn);
      den = den * sc0 + den1 * sc1;
      ac0 = ac0 * sc0 + acbuf[t][c + 0] * sc1;
      ac1 = ac1 * sc0 + acbuf[t][c + 1] * sc1;
      ac2 = ac2 * sc0 + acbuf[t][c + 2] * sc1;
      ac3 = ac3 * sc0 + acbuf[t][c + 3] * sc1;
      m = mn;
    }
    float inv = 1.f / (den + 1e-16f);
    ushort4 o;
    o.x = f2b(ac0 * inv + bias_s[c + 0]);
    o.y = f2b(ac1 * inv + bias_s[c + 1]);
    o.z = f2b(ac2 * inv + bias_s[c + 2]);
    o.w = f2b(ac3 * inv + bias_s[c + 3]);
    *(ushort4*)(xnext + (size_t)nid * 512 + colbase + c) = o;
  }
}

// ---------------- generic MFMA GEMM (A + B LDS-staged, 64-row tile) ----------------
template <bool RELU, bool OBF16>
__global__ __launch_bounds__(256, 2) void mgemm_k(
    const ushort* __restrict__ A, int lda, const ushort* __restrict__ WT, int K,
    const float* __restrict__ bias, void* __restrict__ C, int ldc, int M) {
  __shared__ ushort As[64][40];
  __shared__ ushort Bs[256][40];
  const int tid = threadIdx.x;
  const int wave = tid >> 6, lane = tid & 63;
  const int quad = lane >> 4, l15 = lane & 15;
  const int m0 = blockIdx.x * 64;
  const int ncol0 = blockIdx.y * 256;
  const ushort* WTb = WT + (size_t)ncol0 * K;
  const int arow = tid >> 2, akc = (tid & 3) << 3;
  int am = m0 + arow;
  if (am >= M) am = M - 1;
  f32x4 acc[4][4];
#pragma unroll
  for (int i = 0; i < 4; ++i)
#pragma unroll
    for (int j = 0; j < 4; ++j) acc[i][j] = (f32x4){0.f, 0.f, 0.f, 0.f};
  for (int k0 = 0; k0 < K; k0 += 32) {
    *(uint4*)&As[arow][akc] = *(const uint4*)(A + (size_t)am * lda + k0 + akc);
#pragma unroll
    for (int r = 0; r < 4; ++r) {
      int row = arow + r * 64;
      *(uint4*)&Bs[row][akc] = *(const uint4*)(WTb + (size_t)row * K + k0 + akc);
    }
    __syncthreads();
    bf16x8 bfr[4];
#pragma unroll
    for (int ni = 0; ni < 4; ++ni)
      bfr[ni] = *(const bf16x8*)&Bs[wave * 64 + ni * 16 + l15][quad * 8];
#pragma unroll
    for (int mi = 0; mi < 4; ++mi) {
      bf16x8 af = *(const bf16x8*)&As[mi * 16 + l15][quad * 8];
#pragma unroll
      for (int ni = 0; ni < 4; ++ni) acc[mi][ni] = MFMA16(af, bfr[ni], acc[mi][ni]);
    }
    __syncthreads();
  }
#pragma unroll
  for (int mi = 0; mi < 4; ++mi)
#pragma unroll
    for (int ni = 0; ni < 4; ++ni) {
      int c = ncol0 + wave * 64 + ni * 16 + l15;
      float bv = bias[c];
#pragma unroll
      for (int r = 0; r < 4; ++r) {
        int m = m0 + mi * 16 + quad * 4 + r;
        if (m < M) {
          float v = acc[mi][ni][r] + bv;
          if (RELU) v = fmaxf(v, 0.f);
          if (OBF16) ((ushort*)C)[(size_t)m * ldc + c] = f2b(v);
          else       ((float*)C)[(size_t)m * ldc + c] = v;
        }
      }
    }
}

// ---------------- decoder: dst-ordered tiles, bf16 Z, NN table ----------------
// phase-2 K-loop barrier-free: W1T fragments direct from L2 (shared by all blocks).
__global__ __launch_bounds__(256, 4) void dec3_k(
    const float* __restrict__ attrs1, const ushort* __restrict__ T,
    const ushort* __restrict__ Z, const int* __restrict__ eid,
    const int* __restrict__ srcs1, const int* __restrict__ dsts1,
    const ushort* __restrict__ W1T, const float* __restrict__ b1,
    const float* __restrict__ W2, const float* __restrict__ b2,
    float* __restrict__ out) {
  __shared__ ushort h0[64][264];   // 33.8 KB; red aliased after phase-2
  float* red = (float*)h0;
  const int tid = threadIdx.x;
  const int wave = tid >> 6, lane = tid & 63;
  const int quad = lane >> 4, l15 = lane & 15;
  const int m0 = blockIdx.x * 64;
  const int arow = tid >> 2;
  {
    int gs = srcs1[m0 + arow], gd = dsts1[m0 + arow];
    int i0 = (int)(attrs1[m0 + arow] * 4096.f + 0.5f);
    i0 = i0 < 0 ? 0 : (i0 > 4096 ? 4096 : i0);
    const ushort* tz0 = T + (size_t)i0 * TLD + 1536;
    int c0 = (tid & 3) * 64;
    const ushort* za = Z + (size_t)gs * 512;
    const ushort* zb = Z + (size_t)gd * 512 + 256;
#pragma unroll
    for (int j = 0; j < 16; ++j) {
      int c = c0 + 4 * j;
      ushort4 a = *(const ushort4*)(za + c);
      ushort4 b = *(const ushort4*)(zb + c);
      ushort4 lo = *(const ushort4*)(tz0 + c);
      ushort4 o;
      o.x = f2b(fmaxf(b2f(a.x) + b2f(b.x) + b2f(lo.x), 0.f));
      o.y = f2b(fmaxf(b2f(a.y) + b2f(b.y) + b2f(lo.y), 0.f));
      o.z = f2b(fmaxf(b2f(a.z) + b2f(b.z) + b2f(lo.z), 0.f));
      o.w = f2b(fmaxf(b2f(a.w) + b2f(b.w) + b2f(lo.w), 0.f));
      *(ushort4*)&h0[arow][c] = o;
    }
  }
  __syncthreads();
  // phase 2 (barrier-free): h1 = relu(h0 @ W1 + b1); out = h1 . W2 + b2
  f32x4 acc2[4][4];
#pragma unroll
  for (int i = 0; i < 4; ++i)
#pragma unroll
    for (int j = 0; j < 4; ++j) acc2[i][j] = (f32x4){0.f, 0.f, 0.f, 0.f};
  for (int k0 = 0; k0 < 256; k0 += 32) {
    bf16x8 bfr[4];
#pragma unroll
    for (int ni = 0; ni < 4; ++ni)
      bfr[ni] = *(const bf16x8*)(W1T + (size_t)(wave * 64 + ni * 16 + l15) * 256 + k0 + quad * 8);
#pragma unroll
    for (int mi = 0; mi < 4; ++mi) {
      bf16x8 af = *(const bf16x8*)&h0[mi * 16 + l15][k0 + quad * 8];
#pragma unroll
      for (int ni = 0; ni < 4; ++ni) acc2[mi][ni] = MFMA16(af, bfr[ni], acc2[mi][ni]);
    }
  }
  float part[4][4];
#pragma unroll
  for (int mi = 0; mi < 4; ++mi)
#pragma unroll
    for (int r = 0; r < 4; ++r) part[mi][r] = 0.f;
#pragma unroll
  for (int mi = 0; mi < 4; ++mi)
#pragma unroll
    for (int ni = 0; ni < 4; ++ni) {
      int c = wave * 64 + ni * 16 + l15;
      float bv = b1[c], wv = W2[c];
#pragma unroll
      for (int r = 0; r < 4; ++r) {
        float v = fmaxf(acc2[mi][ni][r] + bv, 0.f);
        part[mi][r] += v * wv;
      }
    }
#pragma unroll
  for (int d = 1; d < 16; d <<= 1)
#pragma unroll
    for (int mi = 0; mi < 4; ++mi)
#pragma unroll
      for (int r = 0; r < 4; ++r) part[mi][r] += __shfl_xor(part[mi][r], d);
  __syncthreads();  // all h0 reads done before aliased red write
  if (l15 == 0)
#pragma unroll
    for (int mi = 0; mi < 4; ++mi)
#pragma unroll
      for (int r = 0; r < 4; ++r) red[wave * 64 + mi * 16 + quad * 4 + r] = part[mi][r];
  __syncthreads();
  if (tid < 64) {
    float s = red[tid] + red[64 + tid] + red[128 + tid] + red[192 + tid];
    out[eid[m0 + tid]] = s + b2[0];
  }
}

// ---------------- host ----------------

extern "C" void kernel_launch(void* const* d_in, const int* in_sizes, int n_in,
                              void* d_out, int out_size, void* d_ws, size_t ws_size,
                              hipStream_t stream) {
  const int*   eidx1  = (const int*)d_in[0];
  const float* eattr1 = (const float*)d_in[1];
  const int*   eidx2  = (const int*)d_in[2];
  const float* eattr2 = (const float*)d_in[3];
  const int*   batch  = (const int*)d_in[4];
  const float* tval   = (const float*)d_in[5];
  const float* te_W0 = (const float*)d_in[6];
  const float* te_b0 = (const float*)d_in[7];
  const float* te_W1 = (const float*)d_in[8];
  const float* te_b1 = (const float*)d_in[9];
  const float* te_W2 = (const float*)d_in[10];
  const float* te_b2 = (const float*)d_in[11];
  const float* ee_W0 = (const float*)d_in[12];
  const float* ee_b0 = (const float*)d_in[13];
  const float* ee_W1 = (const float*)d_in[14];
  const float* ee_b1 = (const float*)d_in[15];
  const float* ee_W2 = (const float*)d_in[16];
  const float* ee_b2 = (const float*)d_in[17];
  const float* dec_W0 = (const float*)d_in[18];
  const float* dec_b0 = (const float*)d_in[19];
  const float* dec_W1 = (const float*)d_in[20];
  const float* dec_b1 = (const float*)d_in[21];
  const float* dec_W2 = (const float*)d_in[22];
  const float* dec_b2 = (const float*)d_in[23];
  const float* gg_Wl  = (const float*)d_in[24];
  const float* gg_bl  = (const float*)d_in[25];
  const float* gg_Wr  = (const float*)d_in[26];
  const float* gg_br  = (const float*)d_in[27];
  const float* gg_We  = (const float*)d_in[28];
  const float* gg_att = (const float*)d_in[29];
  const float* gg_bias= (const float*)d_in[30];
  const float* gf_Wl  = (const float*)d_in[31];
  const float* gf_bl  = (const float*)d_in[32];
  const float* gf_Wr  = (const float*)d_in[33];
  const float* gf_br  = (const float*)d_in[34];
  const float* gf_We  = (const float*)d_in[35];
  const float* gf_att = (const float*)d_in[36];
  const float* gf_bias= (const float*)d_in[37];
  (void)in_sizes; (void)n_in; (void)out_size; (void)ws_size;

  const int* src1 = eidx1;
  const int* dst1 = eidx1 + NE1;
  const int* src2 = eidx2;
  const int* dst2 = eidx2 + NE2;

  char* base = (char*)d_ws;
  size_t off = 0;
  auto alloc = [&](size_t bytes) {
    void* p = base + off;
    off += (bytes + 255) & ~(size_t)255;
    return p;
  };
  ushort* x_a    = (ushort*)alloc((size_t)NNODE * 512 * 2);
  ushort* x_b    = (ushort*)alloc((size_t)NNODE * 512 * 2);
  ushort* xlr    = (ushort*)alloc((size_t)NNODE * 1024 * 2);
  ushort* Z      = (ushort*)alloc((size_t)NNODE * 512 * 2);
  ushort* h0b    = (ushort*)alloc((size_t)TROWS * 256 * 2);
  ushort* H1     = (ushort*)alloc((size_t)TROWS * 256 * 2);
  ushort* T      = (ushort*)alloc((size_t)TROWS * TLD * 2);   // 14.7 MB packed tables
  ushort* WcatT  = (ushort*)alloc((size_t)7 * 256 * 256 * 2);
  float*  bcat   = (float*)alloc((size_t)TLD * 4);
  float*  tenc   = (float*)alloc((size_t)16 * Hd * 4);
  ushort* decZT  = (ushort*)alloc((size_t)512 * 512 * 2);
  ushort* decW1T = (ushort*)alloc((size_t)256 * 256 * 2);
  ushort* eeW1T  = (ushort*)alloc((size_t)256 * 256 * 2);
  ushort* wlrT   = (ushort*)alloc((size_t)6 * 512 * 512 * 2);  // [2*i+g]
  float*  biascat= (float*)alloc((size_t)6 * 1024 * 4);
  float*  zerob  = (float*)alloc((size_t)512 * 4);
  int* cnt1      = (int*)alloc((size_t)NNODE * 4);
  int* cur1      = (int*)alloc((size_t)NNODE * 4);
  int* rs1       = (int*)alloc((size_t)(NNODE + 1) * 4);
  int* eid1      = (int*)alloc((size_t)NE1 * 4);
  int* srcs1     = (int*)alloc((size_t)NE1 * 4);
  float* attrs1  = (float*)alloc((size_t)NE1 * 4);
  int* dsts1     = (int*)alloc((size_t)NE1 * 4);
  int* cnt2      = (int*)alloc((size_t)NNODE * 4);
  int* cur2      = (int*)alloc((size_t)NNODE * 4);
  int* rs2       = (int*)alloc((size_t)(NNODE + 1) * 4);
  int* srcs2     = (int*)alloc((size_t)NE2 * 4);
  float* attrs2  = (float*)alloc((size_t)NE2 * 4);

  float* out = (float*)d_out;

  // ---- merged setup ----
  init_small_k<<<(NNODE + 512 + 6144 + 255) / 256, 256, 0, stream>>>(
      cnt1, cur1, cnt2, cur2, zerob, biascat, gg_bl, gg_br, gf_bl, gf_br);
  fold2_k<<<dim3(256, 7), 256, 0, stream>>>(gg_We, gf_We, dec_W0, dec_b0, ee_W2, ee_b2,
                                            WcatT, bcat);
  build_h0_k<<<TROWS, 256, 0, stream>>>(ee_W0, ee_b0, h0b);

  TransArgs ta;
  int nt = 0, cum = 0;
  auto add = [&](const float* s, ushort* d, int K, int noff, int ld) {
    ta.t[nt].src = s; ta.t[nt].dst = d; ta.t[nt].K = K;
    ta.t[nt].n_off = noff; ta.t[nt].ld = ld; ta.t[nt].start = cum;
    cum += (K / 32) * 8; ++nt;
  };
  add(dec_W1, decW1T, 256, 0, 256);
  add(ee_W1, eeW1T, 256, 0, 256);
  add(dec_W0, decZT, 512, 0, 512);
  add(dec_W0 + 512 * 256, decZT, 512, 256, 512);
  for (int i = 0; i < 3; ++i) {
    add(gg_Wl + (size_t)i * 512 * 256, wlrT + (size_t)(2 * i) * 512 * 512, 512, 0, 512);
    add(gg_Wr + (size_t)i * 512 * 256, wlrT + (size_t)(2 * i) * 512 * 512, 512, 256, 512);
    add(gf_Wl + (size_t)i * 512 * 256, wlrT + (size_t)(2 * i + 1) * 512 * 512, 512, 0, 512);
    add(gf_Wr + (size_t)i * 512 * 256, wlrT + (size_t)(2 * i + 1) * 512 * 512, 512, 256, 512);
  }
  for (int i = nt; i < 24; ++i) ta.t[i].start = 0x7fffffff;
  trans_all_k<<<cum, 256, 0, stream>>>(ta);

  // ---- H1 = relu(h0b @ eeW1T + ee_b1) via MFMA, then table T = H1 @ WcatT + bcat ----
  mgemm_k<true, true><<<dim3((TROWS + 63) / 64, 1), 256, 0, stream>>>(
      h0b, 256, eeW1T, 256, ee_b1, H1, 256, TROWS);
  mgemm_k<false, true><<<dim3((TROWS + 63) / 64, 7), 256, 0, stream>>>(
      H1, 256, WcatT, 256, bcat, T, TLD, TROWS);

  // ---- CSR build ----
  deg_all_k<<<(NE1 + NE2) / 256, 256, 0, stream>>>(dst1, cnt1, dst2, cnt2);
  scan_k<<<2, 640, 0, stream>>>(cnt1, rs1, cnt2, rs2);
  fill_all_k<<<(NE1 + NE2) / 256, 256, 0, stream>>>(
      dst1, rs1, cur1, eid1, src1, eattr1, srcs1, attrs1, dsts1,
      dst2, rs2, cur2, src2, eattr2, srcs2, attrs2);

  // ---- time encoding -> x0 (bf16) ----
  time_mlp_k<<<16, 256, 0, stream>>>(tval, te_W0, te_b0, te_W1, te_b1, te_W2, te_b2, tenc);
  build_x0_k<<<(NNODE * 512) / 256, 256, 0, stream>>>(batch, tenc, x_a);

  ushort* x_cur = x_a;
  ushort* x_nxt = x_b;
  const int ngrid = (NNODE + 63) / 64;
  for (int i = 0; i < 3; ++i) {
    mgemm_k<false, true><<<dim3(ngrid, 4), 256, 0, stream>>>(
        x_cur, 512, wlrT + (size_t)(2 * i) * 512 * 512, 512, biascat + (size_t)i * 1024, xlr, 1024, NNODE);
    attagg_k<<<2 * NNODE, 256, 0, stream>>>(
        T, (2 * i) * 256, (2 * i + 1) * 256,
        gg_att + i * Hd, gf_att + i * Hd, xlr,
        srcs1, attrs1, srcs2, attrs2, rs1, rs2,
        gg_bias + i * Hd, gf_bias + i * Hd, x_nxt);
    ushort* t = x_cur; x_cur = x_nxt; x_nxt = t;
  }

  // ---- decoder: Z (bf16) per-node, then per-edge fused MLP (dst-ordered tiles) ----
  mgemm_k<false, true><<<dim3(ngrid, 2), 256, 0, stream>>>(
      x_cur, 512, decZT, 512, zerob, Z, 512, NNODE);
  dec3_k<<<NE1 / 64, 256, 0, stream>>>(attrs1, T, Z, eid1, srcs1, dsts1,
                                       decW1T, dec_b1, dec_W2, dec_b2, out);
}

// Round 18
// 556.996 us; speedup vs baseline: 1.0418x; 1.0418x over previous
//
#include <hip/hip_runtime.h>

#define Hd 256
#define NNODE 10000
#define NE1 131072
#define NE2 65536
#define TROWS 4097
#define TLD 1792     // 7 * 256 packed table columns

typedef __attribute__((ext_vector_type(8))) short bf16x8;
typedef __attribute__((ext_vector_type(4))) float f32x4;

#define MFMA16(a, b, c) __builtin_amdgcn_mfma_f32_16x16x32_bf16((a), (b), (c), 0, 0, 0)

__device__ __forceinline__ float b2f(ushort u) { return __uint_as_float(((unsigned)u) << 16); }
__device__ __forceinline__ ushort f2b(float f) {
  unsigned u = __float_as_uint(f);
  return (ushort)((u + 0x7fffu + ((u >> 16) & 1u)) >> 16);
}

// ---------------- small kernels ----------------

__global__ void time_mlp_k(const float* __restrict__ tval,
                           const float* __restrict__ W0, const float* __restrict__ b0,
                           const float* __restrict__ W1, const float* __restrict__ b1,
                           const float* __restrict__ W2, const float* __restrict__ b2,
                           float* __restrict__ tenc) {
  __shared__ float h0[Hd], h1[Hd];
  int b = blockIdx.x, j = threadIdx.x;
  float t = tval[b];
  h0[j] = fmaxf(t * W0[j] + b0[j], 0.f);
  __syncthreads();
  float a = b1[j];
  for (int k = 0; k < Hd; ++k) a += h0[k] * W1[k * Hd + j];
  h1[j] = fmaxf(a, 0.f);
  __syncthreads();
  float c = b2[j];
  for (int k = 0; k < Hd; ++k) c += h1[k] * W2[k * Hd + j];
  tenc[b * Hd + j] = c;
}

__global__ void build_x0_k(const int* __restrict__ batch, const float* __restrict__ tenc,
                           ushort* __restrict__ x0) {
  int idx = blockIdx.x * 256 + threadIdx.x;
  int n = idx >> 9;
  x0[idx] = f2b(tenc[batch[n] * Hd + (idx & 255)]);
}

__global__ void init_small_k(int* __restrict__ cnt1, int* __restrict__ cur1,
                             int* __restrict__ cnt2, int* __restrict__ cur2,
                             float* __restrict__ zerob, float* __restrict__ biascat,
                             const float* __restrict__ gg_bl, const float* __restrict__ gg_br,
                             const float* __restrict__ gf_bl, const float* __restrict__ gf_br) {
  int i = blockIdx.x * 256 + threadIdx.x;
  if (i < NNODE) { cnt1[i] = 0; cur1[i] = 0; cnt2[i] = 0; cur2[i] = 0; return; }
  i -= NNODE;
  if (i < 512) { zerob[i] = 0.f; return; }
  i -= 512;
  if (i < 6144) {
    int layer = i >> 10, c = i & 1023;
    float v;
    if (c < 256)      v = gg_bl[layer * 256 + c];
    else if (c < 512) v = gg_br[layer * 256 + c - 256];
    else if (c < 768) v = gf_bl[layer * 256 + c - 512];
    else              v = gf_br[layer * 256 + c - 768];
    biascat[layer * 1024 + c] = v;
  }
}

// Packed fold: WcatT[y][n][k] = sum_j W2[k][j] * Wy[j][n]  (y<6: We[2i+g]; y=6: dec_W0c)
__global__ void fold2_k(const float* __restrict__ gg_We, const float* __restrict__ gf_We,
                        const float* __restrict__ dec_W0, const float* __restrict__ dec_b0,
                        const float* __restrict__ eeW2, const float* __restrict__ eeb2,
                        ushort* __restrict__ WcatT, float* __restrict__ bcat) {
  __shared__ float col[256];
  int n = blockIdx.x, y = blockIdx.y, k = threadIdx.x;
  if (y < 6) {
    int i = y >> 1, g = y & 1;
    const float* src = (g == 0 ? gg_We : gf_We) + (size_t)i * 65536;
    col[k] = src[(size_t)k * 256 + n];
  } else {
    col[k] = dec_W0[(size_t)(1024 + k) * 256 + n];
  }
  __syncthreads();
  float acc = 0.f;
  const float* w2row = eeW2 + (size_t)k * 256;
  for (int j = 0; j < 256; ++j) acc += w2row[j] * col[j];
  WcatT[((size_t)y * 256 + n) * 256 + k] = f2b(acc);
  if (k == 0) {
    float bb = (y == 6) ? dec_b0[n] : 0.f;
    for (int j = 0; j < 256; ++j) bb += eeb2[j] * col[j];
    bcat[y * 256 + n] = bb;
  }
}

// h0b[i][j] = bf16(relu((i/4096)*W0[j] + b0[j]))   (rank-1, elementwise)
__global__ void build_h0_k(const float* __restrict__ W0, const float* __restrict__ b0,
                           ushort* __restrict__ h0b) {
  int i = blockIdx.x, j = threadIdx.x;
  float a = (float)i / 4096.f;
  h0b[(size_t)i * 256 + j] = f2b(fmaxf(a * W0[j] + b0[j], 0.f));
}

// ---------------- merged weight transposes ----------------
struct TT { const float* src; ushort* dst; int K; int n_off; int ld; int start; };
struct TransArgs { TT t[24]; };

__global__ void trans_all_k(TransArgs a) {
  int b = blockIdx.x;
  int ti = 0;
  while (ti + 1 < 24 && a.t[ti + 1].start <= b) ++ti;
  TT tk = a.t[ti];
  int lb = b - tk.start;
  int gx = tk.K >> 5;
  int k0 = (lb % gx) * 32, n0 = (lb / gx) * 32;
  __shared__ float t[32][33];
  int tx = threadIdx.x & 31, ty = threadIdx.x >> 5;
#pragma unroll
  for (int p = 0; p < 4; ++p)
    t[ty + 8 * p][tx] = tk.src[(size_t)(k0 + ty + 8 * p) * 256 + n0 + tx];
  __syncthreads();
#pragma unroll
  for (int p = 0; p < 4; ++p)
    tk.dst[(size_t)(tk.n_off + n0 + ty + 8 * p) * tk.ld + k0 + tx] = f2b(t[tx][ty + 8 * p]);
}

// ---------------- CSR build (by dst) ----------------

__global__ void deg_all_k(const int* __restrict__ dst1, int* __restrict__ cnt1,
                          const int* __restrict__ dst2, int* __restrict__ cnt2) {
  int e = blockIdx.x * 256 + threadIdx.x;
  if (e < NE1) atomicAdd(cnt1 + dst1[e], 1);
  else if (e - NE1 < NE2) atomicAdd(cnt2 + dst2[e - NE1], 1);
}

__global__ void scan_k(const int* __restrict__ cnt1, int* __restrict__ rs1,
                       const int* __restrict__ cnt2, int* __restrict__ rs2) {
  const int g = blockIdx.x;
  const int* cnt = g ? cnt2 : cnt1;
  int* rowstart = g ? rs2 : rs1;
  const int E = g ? NE2 : NE1;
  __shared__ int part[626];
  int t = threadIdx.x;
  if (t < 625) {
    int s = 0;
#pragma unroll
    for (int i = 0; i < 16; ++i) s += cnt[t * 16 + i];
    part[t] = s;
  }
  __syncthreads();
  if (t == 0) {
    int run = 0;
    for (int i = 0; i < 625; ++i) { int v = part[i]; part[i] = run; run += v; }
  }
  __syncthreads();
  if (t < 625) {
    int off = part[t];
#pragma unroll
    for (int i = 0; i < 16; ++i) { rowstart[t * 16 + i] = off; off += cnt[t * 16 + i]; }
  }
  if (t == 0) rowstart[NNODE] = E;
}

// fill CSR + CSR-ordered side arrays
__global__ void fill_all_k(const int* __restrict__ dst1, const int* __restrict__ rs1,
                           int* __restrict__ cur1, int* __restrict__ eid1,
                           const int* __restrict__ src1, const float* __restrict__ eattr1,
                           int* __restrict__ srcs1, float* __restrict__ attrs1,
                           int* __restrict__ dsts1,
                           const int* __restrict__ dst2, const int* __restrict__ rs2,
                           int* __restrict__ cur2,
                           const int* __restrict__ src2, const float* __restrict__ eattr2,
                           int* __restrict__ srcs2, float* __restrict__ attrs2) {
  int e = blockIdx.x * 256 + threadIdx.x;
  if (e < NE1) {
    int d = dst1[e];
    int idx = rs1[d] + atomicAdd(cur1 + d, 1);
    eid1[idx] = e;
    srcs1[idx] = src1[e];
    attrs1[idx] = eattr1[e];
    dsts1[idx] = d;
  } else if (e - NE1 < NE2) {
    int e2 = e - NE1;
    int d = dst2[e2];
    int idx = rs2[d] + atomicAdd(cur2 + d, 1);
    srcs2[idx] = src2[e2];
    attrs2[idx] = eattr2[e2];
  }
}

// ---------------- fused logit + online-softmax aggregate ----------------
// 2 waves per node, pipelined gather, nearest-neighbor table lookup.
__global__ __launch_bounds__(256) void attagg_k(
    const ushort* __restrict__ T, int tcol1, int tcol2,
    const float* __restrict__ att1, const float* __restrict__ att2,
    const ushort* __restrict__ xlr,
    const int* __restrict__ srcs1, const float* __restrict__ attrs1,
    const int* __restrict__ srcs2, const float* __restrict__ attrs2,
    const int* __restrict__ rs1, const int* __restrict__ rs2,
    const float* __restrict__ bias1, const float* __restrict__ bias2,
    ushort* __restrict__ xnext) {
  __shared__ float att_s[2][256], bias_s[2][256];
  __shared__ float acbuf[2][256];
  __shared__ float mden[2][2];
  const int tid = threadIdx.x;
  att_s[0][tid] = att1[tid];
  att_s[1][tid] = att2[tid];
  bias_s[0][tid] = bias1[tid];
  bias_s[1][tid] = bias2[tid];
  __syncthreads();
  const int wave = tid >> 6, lane = tid & 63;
  const int nloc = wave >> 1, sub = wave & 1;
  const bool g1 = blockIdx.x < (NNODE / 2);
  const int nid = (g1 ? blockIdx.x : blockIdx.x - NNODE / 2) * 2 + nloc;
  const int gi = g1 ? 0 : 1;
  const int* srcs = g1 ? srcs1 : srcs2;
  const float* attrs = g1 ? attrs1 : attrs2;
  const int* rowstart = g1 ? rs1 : rs2;
  const int goff = g1 ? 0 : 512;
  const int colbase = g1 ? 0 : 256;
  const ushort* Tg = T + (g1 ? tcol1 : tcol2);
  const int c = lane * 4;
  ushort4 xr4 = *(const ushort4*)(xlr + (size_t)nid * 1024 + goff + 256 + c);
  const float xr0 = b2f(xr4.x), xr1 = b2f(xr4.y), xr2 = b2f(xr4.z), xr3 = b2f(xr4.w);
  const float a0 = att_s[gi][c], a1 = att_s[gi][c + 1];
  const float a2 = att_s[gi][c + 2], a3 = att_s[gi][c + 3];
  const int s0 = rowstart[nid], s1 = rowstart[nid + 1];
  float m = -1e30f;
  float den = 0.f, ac0 = 0.f, ac1 = 0.f, ac2 = 0.f, ac3 = 0.f;
  {
    int i = s0 + sub;
    if (i < s1) {
      ushort4 xv, lo;
      {  // prologue (nearest-neighbor table row)
        int s = srcs[i];
        int i0 = (int)(attrs[i] * 4096.f + 0.5f);
        i0 = i0 < 0 ? 0 : (i0 > 4096 ? 4096 : i0);
        lo = *(const ushort4*)(Tg + (size_t)i0 * TLD + c);
        xv = *(const ushort4*)(xlr + (size_t)s * 1024 + goff + c);
      }
      for (; i < s1; i += 2) {
        ushort4 xv_c = xv, lo_c = lo;
        if (i + 2 < s1) {  // prefetch next edge (this wave's half)
          int s = srcs[i + 2];
          int i0 = (int)(attrs[i + 2] * 4096.f + 0.5f);
          i0 = i0 < 0 ? 0 : (i0 > 4096 ? 4096 : i0);
          lo = *(const ushort4*)(Tg + (size_t)i0 * TLD + c);
          xv = *(const ushort4*)(xlr + (size_t)s * 1024 + goff + c);
        }
        float x0 = b2f(xv_c.x), x1 = b2f(xv_c.y), x2 = b2f(xv_c.z), x3 = b2f(xv_c.w);
        float z0 = x0 + xr0 + b2f(lo_c.x);
        float z1 = x1 + xr1 + b2f(lo_c.y);
        float z2 = x2 + xr2 + b2f(lo_c.z);
        float z3 = x3 + xr3 + b2f(lo_c.w);
        z0 = z0 > 0.f ? z0 : 0.2f * z0;
        z1 = z1 > 0.f ? z1 : 0.2f * z1;
        z2 = z2 > 0.f ? z2 : 0.2f * z2;
        z3 = z3 > 0.f ? z3 : 0.2f * z3;
        float p = z0 * a0 + z1 * a1 + z2 * a2 + z3 * a3;
#pragma unroll
        for (int dd = 1; dd < 64; dd <<= 1) p += __shfl_xor(p, dd);
        float mn = fmaxf(m, p);
        float sc = __expf(m - mn);
        float ww = __expf(p - mn);
        den = den * sc + ww;
        ac0 = ac0 * sc + ww * x0;
        ac1 = ac1 * sc + ww * x1;
        ac2 = ac2 * sc + ww * x2;
        ac3 = ac3 * sc + ww * x3;
        m = mn;
      }
    }
  }
  // merge the two halves through LDS
  if (sub == 1) {
    acbuf[nloc][c + 0] = ac0;
    acbuf[nloc][c + 1] = ac1;
    acbuf[nloc][c + 2] = ac2;
    acbuf[nloc][c + 3] = ac3;
    if (lane == 0) { mden[nloc][0] = m; mden[nloc][1] = den; }
  }
  __syncthreads();
  if (sub == 0) {
    float m1 = mden[nloc][0], den1 = mden[nloc][1];
    float mn = fmaxf(m, m1);
    float sc0 = __expf(m - mn), sc1 = __expf(m1 - mn);
    float d = den * sc0 + den1 * sc1;
    float A0 = ac0 * sc0 + acbuf[nloc][c + 0] * sc1;
    float A1 = ac1 * sc0 + acbuf[nloc][c + 1] * sc1;
    float A2 = ac2 * sc0 + acbuf[nloc][c + 2] * sc1;
    float A3 = ac3 * sc0 + acbuf[nloc][c + 3] * sc1;
    float inv = 1.f / (d + 1e-16f);
    ushort4 o;
    o.x = f2b(A0 * inv + bias_s[gi][c + 0]);
    o.y = f2b(A1 * inv + bias_s[gi][c + 1]);
    o.z = f2b(A2 * inv + bias_s[gi][c + 2]);
    o.w = f2b(A3 * inv + bias_s[gi][c + 3]);
    *(ushort4*)(xnext + (size_t)nid * 512 + colbase + c) = o;
  }
}

// ---------------- generic MFMA GEMM (A + B LDS-staged, 64-row tile) ----------------
template <bool RELU, bool OBF16>
__global__ __launch_bounds__(256, 2) void mgemm_k(
    const ushort* __restrict__ A, int lda, const ushort* __restrict__ WT, int K,
    const float* __restrict__ bias, void* __restrict__ C, int ldc, int M) {
  __shared__ ushort As[64][40];
  __shared__ ushort Bs[256][40];
  const int tid = threadIdx.x;
  const int wave = tid >> 6, lane = tid & 63;
  const int quad = lane >> 4, l15 = lane & 15;
  const int m0 = blockIdx.x * 64;
  const int ncol0 = blockIdx.y * 256;
  const ushort* WTb = WT + (size_t)ncol0 * K;
  const int arow = tid >> 2, akc = (tid & 3) << 3;
  int am = m0 + arow;
  if (am >= M) am = M - 1;
  f32x4 acc[4][4];
#pragma unroll
  for (int i = 0; i < 4; ++i)
#pragma unroll
    for (int j = 0; j < 4; ++j) acc[i][j] = (f32x4){0.f, 0.f, 0.f, 0.f};
  for (int k0 = 0; k0 < K; k0 += 32) {
    *(uint4*)&As[arow][akc] = *(const uint4*)(A + (size_t)am * lda + k0 + akc);
#pragma unroll
    for (int r = 0; r < 4; ++r) {
      int row = arow + r * 64;
      *(uint4*)&Bs[row][akc] = *(const uint4*)(WTb + (size_t)row * K + k0 + akc);
    }
    __syncthreads();
    bf16x8 bfr[4];
#pragma unroll
    for (int ni = 0; ni < 4; ++ni)
      bfr[ni] = *(const bf16x8*)&Bs[wave * 64 + ni * 16 + l15][quad * 8];
#pragma unroll
    for (int mi = 0; mi < 4; ++mi) {
      bf16x8 af = *(const bf16x8*)&As[mi * 16 + l15][quad * 8];
#pragma unroll
      for (int ni = 0; ni < 4; ++ni) acc[mi][ni] = MFMA16(af, bfr[ni], acc[mi][ni]);
    }
    __syncthreads();
  }
#pragma unroll
  for (int mi = 0; mi < 4; ++mi)
#pragma unroll
    for (int ni = 0; ni < 4; ++ni) {
      int c = ncol0 + wave * 64 + ni * 16 + l15;
      float bv = bias[c];
#pragma unroll
      for (int r = 0; r < 4; ++r) {
        int m = m0 + mi * 16 + quad * 4 + r;
        if (m < M) {
          float v = acc[mi][ni][r] + bv;
          if (RELU) v = fmaxf(v, 0.f);
          if (OBF16) ((ushort*)C)[(size_t)m * ldc + c] = f2b(v);
          else       ((float*)C)[(size_t)m * ldc + c] = v;
        }
      }
    }
}

// ---------------- decoder: dst-ordered tiles, bf16 Z, NN table ----------------
// phase-2 K-loop barrier-free: W1T fragments direct from L2 (shared by all blocks).
__global__ __launch_bounds__(256, 4) void dec3_k(
    const float* __restrict__ attrs1, const ushort* __restrict__ T,
    const ushort* __restrict__ Z, const int* __restrict__ eid,
    const int* __restrict__ srcs1, const int* __restrict__ dsts1,
    const ushort* __restrict__ W1T, const float* __restrict__ b1,
    const float* __restrict__ W2, const float* __restrict__ b2,
    float* __restrict__ out) {
  __shared__ ushort h0[64][264];   // 33.8 KB; red aliased after phase-2
  float* red = (float*)h0;
  const int tid = threadIdx.x;
  const int wave = tid >> 6, lane = tid & 63;
  const int quad = lane >> 4, l15 = lane & 15;
  const int m0 = blockIdx.x * 64;
  const int arow = tid >> 2;
  {
    int gs = srcs1[m0 + arow], gd = dsts1[m0 + arow];
    int i0 = (int)(attrs1[m0 + arow] * 4096.f + 0.5f);
    i0 = i0 < 0 ? 0 : (i0 > 4096 ? 4096 : i0);
    const ushort* tz0 = T + (size_t)i0 * TLD + 1536;
    int c0 = (tid & 3) * 64;
    const ushort* za = Z + (size_t)gs * 512;
    const ushort* zb = Z + (size_t)gd * 512 + 256;
#pragma unroll
    for (int j = 0; j < 16; ++j) {
      int c = c0 + 4 * j;
      ushort4 a = *(const ushort4*)(za + c);
      ushort4 b = *(const ushort4*)(zb + c);
      ushort4 lo = *(const ushort4*)(tz0 + c);
      ushort4 o;
      o.x = f2b(fmaxf(b2f(a.x) + b2f(b.x) + b2f(lo.x), 0.f));
      o.y = f2b(fmaxf(b2f(a.y) + b2f(b.y) + b2f(lo.y), 0.f));
      o.z = f2b(fmaxf(b2f(a.z) + b2f(b.z) + b2f(lo.z), 0.f));
      o.w = f2b(fmaxf(b2f(a.w) + b2f(b.w) + b2f(lo.w), 0.f));
      *(ushort4*)&h0[arow][c] = o;
    }
  }
  __syncthreads();
  // phase 2 (barrier-free): h1 = relu(h0 @ W1 + b1); out = h1 . W2 + b2
  f32x4 acc2[4][4];
#pragma unroll
  for (int i = 0; i < 4; ++i)
#pragma unroll
    for (int j = 0; j < 4; ++j) acc2[i][j] = (f32x4){0.f, 0.f, 0.f, 0.f};
  for (int k0 = 0; k0 < 256; k0 += 32) {
    bf16x8 bfr[4];
#pragma unroll
    for (int ni = 0; ni < 4; ++ni)
      bfr[ni] = *(const bf16x8*)(W1T + (size_t)(wave * 64 + ni * 16 + l15) * 256 + k0 + quad * 8);
#pragma unroll
    for (int mi = 0; mi < 4; ++mi) {
      bf16x8 af = *(const bf16x8*)&h0[mi * 16 + l15][k0 + quad * 8];
#pragma unroll
      for (int ni = 0; ni < 4; ++ni) acc2[mi][ni] = MFMA16(af, bfr[ni], acc2[mi][ni]);
    }
  }
  float part[4][4];
#pragma unroll
  for (int mi = 0; mi < 4; ++mi)
#pragma unroll
    for (int r = 0; r < 4; ++r) part[mi][r] = 0.f;
#pragma unroll
  for (int mi = 0; mi < 4; ++mi)
#pragma unroll
    for (int ni = 0; ni < 4; ++ni) {
      int c = wave * 64 + ni * 16 + l15;
      float bv = b1[c], wv = W2[c];
#pragma unroll
      for (int r = 0; r < 4; ++r) {
        float v = fmaxf(acc2[mi][ni][r] + bv, 0.f);
        part[mi][r] += v * wv;
      }
    }
#pragma unroll
  for (int d = 1; d < 16; d <<= 1)
#pragma unroll
    for (int mi = 0; mi < 4; ++mi)
#pragma unroll
      for (int r = 0; r < 4; ++r) part[mi][r] += __shfl_xor(part[mi][r], d);
  __syncthreads();  // all h0 reads done before aliased red write
  if (l15 == 0)
#pragma unroll
    for (int mi = 0; mi < 4; ++mi)
#pragma unroll
      for (int r = 0; r < 4; ++r) red[wave * 64 + mi * 16 + quad * 4 + r] = part[mi][r];
  __syncthreads();
  if (tid < 64) {
    float s = red[tid] + red[64 + tid] + red[128 + tid] + red[192 + tid];
    out[eid[m0 + tid]] = s + b2[0];
  }
}

// ---------------- host ----------------

extern "C" void kernel_launch(void* const* d_in, const int* in_sizes, int n_in,
                              void* d_out, int out_size, void* d_ws, size_t ws_size,
                              hipStream_t stream) {
  const int*   eidx1  = (const int*)d_in[0];
  const float* eattr1 = (const float*)d_in[1];
  const int*   eidx2  = (const int*)d_in[2];
  const float* eattr2 = (const float*)d_in[3];
  const int*   batch  = (const int*)d_in[4];
  const float* tval   = (const float*)d_in[5];
  const float* te_W0 = (const float*)d_in[6];
  const float* te_b0 = (const float*)d_in[7];
  const float* te_W1 = (const float*)d_in[8];
  const float* te_b1 = (const float*)d_in[9];
  const float* te_W2 = (const float*)d_in[10];
  const float* te_b2 = (const float*)d_in[11];
  const float* ee_W0 = (const float*)d_in[12];
  const float* ee_b0 = (const float*)d_in[13];
  const float* ee_W1 = (const float*)d_in[14];
  const float* ee_b1 = (const float*)d_in[15];
  const float* ee_W2 = (const float*)d_in[16];
  const float* ee_b2 = (const float*)d_in[17];
  const float* dec_W0 = (const float*)d_in[18];
  const float* dec_b0 = (const float*)d_in[19];
  const float* dec_W1 = (const float*)d_in[20];
  const float* dec_b1 = (const float*)d_in[21];
  const float* dec_W2 = (const float*)d_in[22];
  const float* dec_b2 = (const float*)d_in[23];
  const float* gg_Wl  = (const float*)d_in[24];
  const float* gg_bl  = (const float*)d_in[25];
  const float* gg_Wr  = (const float*)d_in[26];
  const float* gg_br  = (const float*)d_in[27];
  const float* gg_We  = (const float*)d_in[28];
  const float* gg_att = (const float*)d_in[29];
  const float* gg_bias= (const float*)d_in[30];
  const float* gf_Wl  = (const float*)d_in[31];
  const float* gf_bl  = (const float*)d_in[32];
  const float* gf_Wr  = (const float*)d_in[33];
  const float* gf_br  = (const float*)d_in[34];
  const float* gf_We  = (const float*)d_in[35];
  const float* gf_att = (const float*)d_in[36];
  const float* gf_bias= (const float*)d_in[37];
  (void)in_sizes; (void)n_in; (void)out_size; (void)ws_size;

  const int* src1 = eidx1;
  const int* dst1 = eidx1 + NE1;
  const int* src2 = eidx2;
  const int* dst2 = eidx2 + NE2;

  char* base = (char*)d_ws;
  size_t off = 0;
  auto alloc = [&](size_t bytes) {
    void* p = base + off;
    off += (bytes + 255) & ~(size_t)255;
    return p;
  };
  ushort* x_a    = (ushort*)alloc((size_t)NNODE * 512 * 2);
  ushort* x_b    = (ushort*)alloc((size_t)NNODE * 512 * 2);
  ushort* xlr    = (ushort*)alloc((size_t)NNODE * 1024 * 2);
  ushort* Z      = (ushort*)alloc((size_t)NNODE * 512 * 2);
  ushort* h0b    = (ushort*)alloc((size_t)TROWS * 256 * 2);
  ushort* H1     = (ushort*)alloc((size_t)TROWS * 256 * 2);
  ushort* T      = (ushort*)alloc((size_t)TROWS * TLD * 2);   // 14.7 MB packed tables
  ushort* WcatT  = (ushort*)alloc((size_t)7 * 256 * 256 * 2);
  float*  bcat   = (float*)alloc((size_t)TLD * 4);
  float*  tenc   = (float*)alloc((size_t)16 * Hd * 4);
  ushort* decZT  = (ushort*)alloc((size_t)512 * 512 * 2);
  ushort* decW1T = (ushort*)alloc((size_t)256 * 256 * 2);
  ushort* eeW1T  = (ushort*)alloc((size_t)256 * 256 * 2);
  ushort* wlrT   = (ushort*)alloc((size_t)6 * 512 * 512 * 2);  // [2*i+g]
  float*  biascat= (float*)alloc((size_t)6 * 1024 * 4);
  float*  zerob  = (float*)alloc((size_t)512 * 4);
  int* cnt1      = (int*)alloc((size_t)NNODE * 4);
  int* cur1      = (int*)alloc((size_t)NNODE * 4);
  int* rs1       = (int*)alloc((size_t)(NNODE + 1) * 4);
  int* eid1      = (int*)alloc((size_t)NE1 * 4);
  int* srcs1     = (int*)alloc((size_t)NE1 * 4);
  float* attrs1  = (float*)alloc((size_t)NE1 * 4);
  int* dsts1     = (int*)alloc((size_t)NE1 * 4);
  int* cnt2      = (int*)alloc((size_t)NNODE * 4);
  int* cur2      = (int*)alloc((size_t)NNODE * 4);
  int* rs2       = (int*)alloc((size_t)(NNODE + 1) * 4);
  int* srcs2     = (int*)alloc((size_t)NE2 * 4);
  float* attrs2  = (float*)alloc((size_t)NE2 * 4);

  float* out = (float*)d_out;

  // ---- merged setup ----
  init_small_k<<<(NNODE + 512 + 6144 + 255) / 256, 256, 0, stream>>>(
      cnt1, cur1, cnt2, cur2, zerob, biascat, gg_bl, gg_br, gf_bl, gf_br);
  fold2_k<<<dim3(256, 7), 256, 0, stream>>>(gg_We, gf_We, dec_W0, dec_b0, ee_W2, ee_b2,
                                            WcatT, bcat);
  build_h0_k<<<TROWS, 256, 0, stream>>>(ee_W0, ee_b0, h0b);

  TransArgs ta;
  int nt = 0, cum = 0;
  auto add = [&](const float* s, ushort* d, int K, int noff, int ld) {
    ta.t[nt].src = s; ta.t[nt].dst = d; ta.t[nt].K = K;
    ta.t[nt].n_off = noff; ta.t[nt].ld = ld; ta.t[nt].start = cum;
    cum += (K / 32) * 8; ++nt;
  };
  add(dec_W1, decW1T, 256, 0, 256);
  add(ee_W1, eeW1T, 256, 0, 256);
  add(dec_W0, decZT, 512, 0, 512);
  add(dec_W0 + 512 * 256, decZT, 512, 256, 512);
  for (int i = 0; i < 3; ++i) {
    add(gg_Wl + (size_t)i * 512 * 256, wlrT + (size_t)(2 * i) * 512 * 512, 512, 0, 512);
    add(gg_Wr + (size_t)i * 512 * 256, wlrT + (size_t)(2 * i) * 512 * 512, 512, 256, 512);
    add(gf_Wl + (size_t)i * 512 * 256, wlrT + (size_t)(2 * i + 1) * 512 * 512, 512, 0, 512);
    add(gf_Wr + (size_t)i * 512 * 256, wlrT + (size_t)(2 * i + 1) * 512 * 512, 512, 256, 512);
  }
  for (int i = nt; i < 24; ++i) ta.t[i].start = 0x7fffffff;
  trans_all_k<<<cum, 256, 0, stream>>>(ta);

  // ---- H1 = relu(h0b @ eeW1T + ee_b1) via MFMA, then table T = H1 @ WcatT + bcat ----
  mgemm_k<true, true><<<dim3((TROWS + 63) / 64, 1), 256, 0, stream>>>(
      h0b, 256, eeW1T, 256, ee_b1, H1, 256, TROWS);
  mgemm_k<false, true><<<dim3((TROWS + 63) / 64, 7), 256, 0, stream>>>(
      H1, 256, WcatT, 256, bcat, T, TLD, TROWS);

  // ---- CSR build ----
  deg_all_k<<<(NE1 + NE2) / 256, 256, 0, stream>>>(dst1, cnt1, dst2, cnt2);
  scan_k<<<2, 640, 0, stream>>>(cnt1, rs1, cnt2, rs2);
  fill_all_k<<<(NE1 + NE2) / 256, 256, 0, stream>>>(
      dst1, rs1, cur1, eid1, src1, eattr1, srcs1, attrs1, dsts1,
      dst2, rs2, cur2, src2, eattr2, srcs2, attrs2);

  // ---- time encoding -> x0 (bf16) ----
  time_mlp_k<<<16, 256, 0, stream>>>(tval, te_W0, te_b0, te_W1, te_b1, te_W2, te_b2, tenc);
  build_x0_k<<<(NNODE * 512) / 256, 256, 0, stream>>>(batch, tenc, x_a);

  ushort* x_cur = x_a;
  ushort* x_nxt = x_b;
  const int ngrid = (NNODE + 63) / 64;
  for (int i = 0; i < 3; ++i) {
    mgemm_k<false, true><<<dim3(ngrid, 4), 256, 0, stream>>>(
        x_cur, 512, wlrT + (size_t)(2 * i) * 512 * 512, 512, biascat + (size_t)i * 1024, xlr, 1024, NNODE);
    attagg_k<<<NNODE, 256, 0, stream>>>(
        T, (2 * i) * 256, (2 * i + 1) * 256,
        gg_att + i * Hd, gf_att + i * Hd, xlr,
        srcs1, attrs1, srcs2, attrs2, rs1, rs2,
        gg_bias + i * Hd, gf_bias + i * Hd, x_nxt);
    ushort* t = x_cur; x_cur = x_nxt; x_nxt = t;
  }

  // ---- decoder: Z (bf16) per-node, then per-edge fused MLP (dst-ordered tiles) ----
  mgemm_k<false, true><<<dim3(ngrid, 2), 256, 0, stream>>>(
      x_cur, 512, decZT, 512, zerob, Z, 512, NNODE);
  dec3_k<<<NE1 / 64, 256, 0, stream>>>(attrs1, T, Z, eid1, srcs1, dsts1,
                                       decW1T, dec_b1, dec_W2, dec_b2, out);
}